// Round 16
// baseline (83.493 us; speedup 1.0000x reference)
//
#include <hip/hip_runtime.h>
#include <hip/hip_bf16.h>

typedef __bf16 bf16x8 __attribute__((ext_vector_type(8)));
typedef float  f32x4  __attribute__((ext_vector_type(4)));

// Async global->LDS DMA (no register result: compiler cannot re-roll/sink it).
__device__ __forceinline__ void dma16(const float* g, float* l) {
    typedef const __attribute__((address_space(1))) unsigned int* gp_t;
    typedef __attribute__((address_space(3))) unsigned int*       lp_t;
    __builtin_amdgcn_global_load_lds((gp_t)(const void*)g, (lp_t)(void*)l, 16, 0, 0);
}

// r11 mechanism, two fixes (latency-depth + flush removal):
// - ONE 512-thr block per CU (grid 256 = 64c x 4grp): B staged once (32 KB)
//   frees LDS for DEPTH-4 per-wave rings (8 x 4 x 4 KB = 128 KB; 160 KB total).
//   DMA gap 3->4 steps over the round-trip.
// - r11's chunk-boundary 64-store burst + vmcnt(24) was a full pipeline flush
//   every 16 steps (drained all 12 loads + ~40 stores). Stores now spread
//   16/step over the next chunk's locals 0-3; exact in-order vmcnt table:
//   base 12; near store-steps 28/44/60; tail 8/4/0. Never 0 mid-loop, <=63.
// - sched_barrier(0x0F): DS+VMEM pinned per step (DMA->ds_read ordering is
//   invisible to the compiler), ALU/VALU/SALU/MFMA free to cross steps.
// Everything else r9/r11-proven: pre-swizzled DMA source (linear dest, XOR
// rr<<4 on read, 0 conflicts), zero main-loop barriers, NT stores (r15:
// cached stores lengthen the DMA RT), bfr register-held per kb.
__global__ __launch_bounds__(512, 2) void sparse_linear_kernel(
    const float* __restrict__ A, const float* __restrict__ Bd,
    const int* __restrict__ rowi, const int* __restrict__ di,
    float* __restrict__ C)
{
    __shared__ __align__(16) float Aring[8][4][1024];          // 128 KB
    __shared__ __align__(16) unsigned short Bt[4 * 64 * 64];   // 32 KB
    char* BtB = (char*)Bt;

    const int bid = blockIdx.x;
    const int c   = bid & 63;
    const int grp = bid >> 6;          // 0..3 -> rows [grp*2048, +2048)
    const int t    = threadIdx.x;
    const int lane = t & 63;
    const int w    = t >> 6;           // 0..7

    int ds[4], koff[4];
    #pragma unroll
    for (int s = 0; s < 4; ++s) {
        koff[s] = rowi[s * 64 + c] * 64;
        ds[s]   = di[s * 64 + c];
    }

    const long wrow0 = (long)grp * 2048 + w * 256;   // + q*64 + mt*16

    // DMA one 16x64 fp32 step-tile (chunk q, k-block kb, m-tile mt) into slot.
    auto dmaA = [&](int q, int kb, int mt, int slot) {
        float* slotp = &Aring[w][slot][0];
        const long rbase = wrow0 + q * 64 + mt * 16;
        #pragma unroll
        for (int i = 0; i < 4; ++i) {
            const int rr  = i * 4 + (lane >> 4);
            const int kfl = (((lane & 15) * 16) ^ (rr << 4)) >> 2;
            const float* g = A + (rbase + rr) * 4096 + koff[kb] + kfl;
            dma16(g, slotp + i * 256);
        }
    };

    // ---- prologue: fill slots 0..3 = steps 0..3 (q=0, kb=0, mt=0..3) ----
    dmaA(0, 0, 0, 0);
    dmaA(0, 0, 1, 1);
    dmaA(0, 0, 2, 2);
    dmaA(0, 0, 3, 3);

    // ---- stage B once: 512 thr; thread -> (block sb, k-half kh, column n) ----
    {
        const int n  = t & 63;
        const int kh = (t >> 6) & 1;
        const int sb = t >> 7;
        const float* Bg = Bd + (long)ds[sb] * 64 + (long)kh * 32 * 16384 + n;
        char* dst = BtB + sb * 8192 + n * 128;
        const int sw = (n & 7) << 4;
        #pragma unroll
        for (int k4 = 0; k4 < 8; ++k4) {
            union { ushort4 u4; __bf16 e[4]; } pk;
            pk.e[0] = (__bf16)Bg[(long)(4 * k4 + 0) * 16384];
            pk.e[1] = (__bf16)Bg[(long)(4 * k4 + 1) * 16384];
            pk.e[2] = (__bf16)Bg[(long)(4 * k4 + 2) * 16384];
            pk.e[3] = (__bf16)Bg[(long)(4 * k4 + 3) * 16384];
            *(ushort4*)(dst + ((kh * 64 + 8 * k4) ^ sw)) = pk.u4;
        }
    }
    __syncthreads();   // the only barrier (drains prologue DMAs + B writes)

    f32x4 acc[4][4];   // [mt][n2] of the current chunk
    #pragma unroll
    for (int m = 0; m < 4; ++m)
        #pragma unroll
        for (int n2 = 0; n2 < 4; ++n2) acc[m][n2] = f32x4{0.f, 0.f, 0.f, 0.f};

    bf16x8 bfr[2][4];  // B fragments of current kb, register-held 4 steps

    #pragma unroll
    for (int q = 0; q < 4; ++q) {
        #pragma unroll
        for (int local = 0; local < 16; ++local) {
            const int st = q * 16 + local;
            const int kb = local >> 2, mt = local & 3;
            const int slot = st & 3;

            // Exact in-order counted wait (target = refill issued at st-4).
            // Younger ops = 3 steps x 4 loads + 16 stores per store-step among
            // them (store-steps are locals 0-3 of chunks q>=1). Tail: refills
            // stop at st>=60.
            if (q == 3 && local == 13)      asm volatile("s_waitcnt vmcnt(8)"  ::: "memory");
            else if (q == 3 && local == 14) asm volatile("s_waitcnt vmcnt(4)"  ::: "memory");
            else if (q == 3 && local == 15) asm volatile("s_waitcnt vmcnt(0)"  ::: "memory");
            else if (q >= 1 && (local == 1 || local == 6))
                                            asm volatile("s_waitcnt vmcnt(28)" ::: "memory");
            else if (q >= 1 && (local == 2 || local == 5))
                                            asm volatile("s_waitcnt vmcnt(44)" ::: "memory");
            else if (q >= 1 && (local == 3 || local == 4))
                                            asm volatile("s_waitcnt vmcnt(60)" ::: "memory");
            else                            asm volatile("s_waitcnt vmcnt(12)" ::: "memory");
            // DS + VMEM pinned to this step; ALU/VALU/SALU/MFMA may cross.
            __builtin_amdgcn_sched_barrier(0x0F);

            // Spread prev-chunk C stores: 16 NT dwords at locals 0-3 (q>=1).
            if (q >= 1 && local < 4) {
                const int mts = local;
                const long crow0 = wrow0 + (q - 1) * 64 + mts * 16 + (lane >> 4) * 4;
                const long col0  = (long)c * 64 + (lane & 15);
                #pragma unroll
                for (int n2 = 0; n2 < 4; ++n2) {
                    #pragma unroll
                    for (int v = 0; v < 4; ++v)
                        __builtin_nontemporal_store(acc[mts][n2][v],
                            &C[(crow0 + v) * 4096 + col0 + n2 * 16]);
                    acc[mts][n2] = f32x4{0.f, 0.f, 0.f, 0.f};
                }
            }

            // B fragments: refresh once per kb (register-held across 4 steps)
            if (mt == 0) {
                const char* bbase = BtB + kb * 8192;
                #pragma unroll
                for (int kh = 0; kh < 2; ++kh)
                    #pragma unroll
                    for (int n2 = 0; n2 < 4; ++n2) {
                        const int nr = n2 * 16 + (lane & 15);
                        const int kbyte = kh * 64 + (lane >> 4) * 16;
                        bfr[kh][n2] = *(const bf16x8*)(bbase + nr * 128 + (kbyte ^ ((nr & 7) << 4)));
                    }
            }

            // A fragment: swizzled read from ring slot; convert fp32->bf16
            const char* ab = (const char*)&Aring[w][slot][0];
            const int r   = lane & 15;
            const int q32 = (lane >> 4) * 32;
            f32x4 a0 = *(const f32x4*)(ab + r * 256 + ((q32)            ^ (r << 4)));
            f32x4 a1 = *(const f32x4*)(ab + r * 256 + ((q32 + 16)       ^ (r << 4)));
            f32x4 a2 = *(const f32x4*)(ab + r * 256 + ((128 + q32)      ^ (r << 4)));
            f32x4 a3 = *(const f32x4*)(ab + r * 256 + ((128 + q32 + 16) ^ (r << 4)));
            union { bf16x8 v; __bf16 e[8]; } af0, af1;
            #pragma unroll
            for (int i = 0; i < 4; ++i) {
                af0.e[i]     = (__bf16)a0[i];
                af0.e[i + 4] = (__bf16)a1[i];
                af1.e[i]     = (__bf16)a2[i];
                af1.e[i + 4] = (__bf16)a3[i];
            }

            // Refill this slot for step st+4 (none for st >= 60).
            if (st + 4 < 64) {
                const int st2 = st + 4;
                dmaA(st2 >> 4, (st2 >> 2) & 3, st2 & 3, slot);
            }

            // 8 MFMAs for this (kb, mt)
            __builtin_amdgcn_s_setprio(1);
            #pragma unroll
            for (int kh = 0; kh < 2; ++kh) {
                const bf16x8 afv = kh ? af1.v : af0.v;
                #pragma unroll
                for (int n2 = 0; n2 < 4; ++n2)
                    acc[mt][n2] = __builtin_amdgcn_mfma_f32_16x16x32_bf16(afv, bfr[kh][n2], acc[mt][n2], 0, 0, 0);
            }
            __builtin_amdgcn_s_setprio(0);
        }
    }

    // ---- epilogue: drain, then store chunk 3 ----
    asm volatile("s_waitcnt vmcnt(0)" ::: "memory");
    #pragma unroll
    for (int mts = 0; mts < 4; ++mts) {
        const long crow0 = wrow0 + 3 * 64 + mts * 16 + (lane >> 4) * 4;
        const long col0  = (long)c * 64 + (lane & 15);
        #pragma unroll
        for (int n2 = 0; n2 < 4; ++n2)
            #pragma unroll
            for (int v = 0; v < 4; ++v)
                __builtin_nontemporal_store(acc[mts][n2][v],
                    &C[(crow0 + v) * 4096 + col0 + n2 * 16]);
    }
}

extern "C" void kernel_launch(void* const* d_in, const int* in_sizes, int n_in,
                              void* d_out, int out_size, void* d_ws, size_t ws_size,
                              hipStream_t stream) {
    const float* A    = (const float*)d_in[0];
    const float* Bd   = (const float*)d_in[1];
    const int*   rowi = (const int*)d_in[2];
    const int*   di   = (const int*)d_in[3];
    float*       C    = (float*)d_out;

    dim3 grid(4 * 64);    // 4 row-groups x 64 columns = 256 blocks = 1/CU
    dim3 block(512);
    hipLaunchKernelGGL(sparse_linear_kernel, grid, block, 0, stream,
                       A, Bd, rowi, di, C);
}